// Round 5
// baseline (3617.090 us; speedup 1.0000x reference)
//
#include <hip/hip_runtime.h>

#define DEV __device__ __forceinline__

typedef unsigned short u16;
typedef short bf16x8 __attribute__((ext_vector_type(8)));
typedef float f32x4 __attribute__((ext_vector_type(4)));

constexpr int Bc = 2, Sc = 4096, Dc = 768, Hc = 12, Lc = 12;
constexpr int BSc = 16, NBc = 256, NRc = 2, DFFc = 3072;
constexpr int Mr = Bc * Sc; // 8192 token rows

DEV u16 f2b(float f) {
  unsigned u = __builtin_bit_cast(unsigned, f);
  u += 0x7fffu + ((u >> 16) & 1u);
  return (u16)(u >> 16);
}
DEV float b2f(u16 u) { return __builtin_bit_cast(float, (unsigned)u << 16); }

DEV void gload_lds16(const void* g, void* l) {
  __builtin_amdgcn_global_load_lds((const __attribute__((address_space(1))) void*)g,
                                   (__attribute__((address_space(3))) void*)l, 16, 0, 0);
}

// ================================================================ gemmP
// 128(M)x256(N) tile, BK=64, 8 waves (2M x 4N), wave-tile 64x64.
// Double-buffered LDS (96KB), 4 fine phases/K-tile, counted vmcnt(6),
// T2 both-sides XOR swizzle, T5 setprio, bijective XCD swizzle.
// C = A[M,K] @ Bt[N,K]^T + bias.
// EPI 1: GELU->bf16 Cb | 2: QKV scatter (Qh/Kh/VhT).
template<int EPI>
__global__ __launch_bounds__(512, 1)
void gemmP(const u16* __restrict__ A, const u16* __restrict__ Bt,
           const float* __restrict__ bias, u16* __restrict__ Cb,
           u16* __restrict__ Qh, u16* __restrict__ Kh,
           u16* __restrict__ VhT, int M, int N, int K)
{
  __shared__ u16 As[2][128 * 64];   // 32 KB
  __shared__ u16 Bs[2][256 * 64];   // 64 KB
  const int tid = threadIdx.x;
  const int wid = tid >> 6, lane = tid & 63;
  const int fr = lane & 15, fq = lane >> 4;
  const int wr = wid >> 2, wc = wid & 3;

  // bijective XCD swizzle (nwg % 8 == 0 for all our launches)
  int nwg = gridDim.x * gridDim.y;
  int orig = blockIdx.y * gridDim.x + blockIdx.x;
  int swz = (nwg & 7) ? orig : (orig & 7) * (nwg >> 3) + (orig >> 3);
  int bx = swz % gridDim.x, by = swz / gridDim.x;
  const int m0 = by * 128, n0 = bx * 256;

  const u16* asrc[2];
  const u16* bsrc[4];
#pragma unroll
  for (int p = 0; p < 2; ++p) {
    int ci = p * 512 + tid;
    int r = ci >> 3, c = (ci & 7) ^ (r & 7);
    asrc[p] = A + (size_t)(m0 + r) * K + c * 8;
  }
#pragma unroll
  for (int p = 0; p < 4; ++p) {
    int ci = p * 512 + tid;
    int r = ci >> 3, c = (ci & 7) ^ (r & 7);
    bsrc[p] = Bt + (size_t)(n0 + r) * K + c * 8;
  }
  auto stageA = [&](int buf, int k0) {
#pragma unroll
    for (int p = 0; p < 2; ++p)
      gload_lds16(asrc[p] + k0, &As[buf][(p * 512 + tid) * 8]);
  };
  auto stageB = [&](int buf, int k0) {
#pragma unroll
    for (int p = 0; p < 4; ++p)
      gload_lds16(bsrc[p] + k0, &Bs[buf][(p * 512 + tid) * 8]);
  };

  f32x4 acc[4][4] = {};
  const int arow = wr * 64 + fr;
  const int brow = wc * 64 + fr;

  stageA(0, 0);  stageB(0, 0);    // tile 0: 6 loads
  stageA(1, 64); stageB(1, 64);   // tile 1: 6 loads
  asm volatile("s_waitcnt vmcnt(6)" ::: "memory");   // tile 0 ready
  __builtin_amdgcn_sched_barrier(0);
  __builtin_amdgcn_s_barrier();

  const int nt = K >> 6;
  for (int kt = 0; kt < nt; ++kt) {
    const u16* ab = As[kt & 1];
    const u16* bb = Bs[kt & 1];
    bf16x8 aA[2][2], aB[2][2], bA[2][2], bB[2][2];  // [frag][khalf]

    // ---- phase 0: read A(m0,1) + B(n0,1); MFMA quadrant (m01 x n01)
#pragma unroll
    for (int f = 0; f < 2; ++f)
#pragma unroll
      for (int kh = 0; kh < 2; ++kh) {
        int rowa = arow + f * 16;
        aA[f][kh] = *(const bf16x8*)(ab + rowa * 64 + (((kh * 4 + fq) ^ (rowa & 7)) << 3));
        int rowb = brow + f * 16;
        bA[f][kh] = *(const bf16x8*)(bb + rowb * 64 + (((kh * 4 + fq) ^ (rowb & 7)) << 3));
      }
    __builtin_amdgcn_s_setprio(1);
#pragma unroll
    for (int m = 0; m < 2; ++m)
#pragma unroll
      for (int n = 0; n < 2; ++n)
#pragma unroll
        for (int kh = 0; kh < 2; ++kh)
          acc[m][n] = __builtin_amdgcn_mfma_f32_16x16x32_bf16(aA[m][kh], bA[n][kh], acc[m][n], 0, 0, 0);
    __builtin_amdgcn_s_setprio(0);

    // ---- phase 1: read B(n2,3); MFMA (m01 x n23); barrier (B fully vacated)
#pragma unroll
    for (int f = 0; f < 2; ++f)
#pragma unroll
      for (int kh = 0; kh < 2; ++kh) {
        int rowb = brow + 32 + f * 16;
        bB[f][kh] = *(const bf16x8*)(bb + rowb * 64 + (((kh * 4 + fq) ^ (rowb & 7)) << 3));
      }
    __builtin_amdgcn_s_setprio(1);
#pragma unroll
    for (int m = 0; m < 2; ++m)
#pragma unroll
      for (int n = 0; n < 2; ++n)
#pragma unroll
        for (int kh = 0; kh < 2; ++kh)
          acc[m][n + 2] = __builtin_amdgcn_mfma_f32_16x16x32_bf16(aA[m][kh], bB[n][kh], acc[m][n + 2], 0, 0, 0);
    __builtin_amdgcn_s_setprio(0);
    asm volatile("s_waitcnt lgkmcnt(0)" ::: "memory");
    __builtin_amdgcn_sched_barrier(0);
    __builtin_amdgcn_s_barrier();

    // ---- phase 2: stage next B into vacated region; read A(m2,3); MFMA (m23 x n01)
    if (kt + 2 < nt) stageB(kt & 1, (kt + 2) * 64);
#pragma unroll
    for (int f = 0; f < 2; ++f)
#pragma unroll
      for (int kh = 0; kh < 2; ++kh) {
        int rowa = arow + 32 + f * 16;
        aB[f][kh] = *(const bf16x8*)(ab + rowa * 64 + (((kh * 4 + fq) ^ (rowa & 7)) << 3));
      }
    __builtin_amdgcn_s_setprio(1);
#pragma unroll
    for (int m = 0; m < 2; ++m)
#pragma unroll
      for (int n = 0; n < 2; ++n)
#pragma unroll
        for (int kh = 0; kh < 2; ++kh)
          acc[m + 2][n] = __builtin_amdgcn_mfma_f32_16x16x32_bf16(aB[m][kh], bA[n][kh], acc[m + 2][n], 0, 0, 0);
    __builtin_amdgcn_s_setprio(0);
    asm volatile("s_waitcnt lgkmcnt(0)" ::: "memory");
    __builtin_amdgcn_sched_barrier(0);
    __builtin_amdgcn_s_barrier();

    // ---- phase 3: stage next A (A fully vacated); MFMA (m23 x n23); tile gate
    if (kt + 2 < nt) stageA(kt & 1, (kt + 2) * 64);
    __builtin_amdgcn_s_setprio(1);
#pragma unroll
    for (int m = 0; m < 2; ++m)
#pragma unroll
      for (int n = 0; n < 2; ++n)
#pragma unroll
        for (int kh = 0; kh < 2; ++kh)
          acc[m + 2][n + 2] = __builtin_amdgcn_mfma_f32_16x16x32_bf16(aB[m][kh], bB[n][kh], acc[m + 2][n + 2], 0, 0, 0);
    __builtin_amdgcn_s_setprio(0);
    if (kt + 1 < nt) {
      if (kt + 2 < nt) asm volatile("s_waitcnt vmcnt(6)" ::: "memory");  // next tile ready, 6 newest in flight
      else             asm volatile("s_waitcnt vmcnt(0)" ::: "memory");
      __builtin_amdgcn_sched_barrier(0);
      __builtin_amdgcn_s_barrier();
    }
  }

  // epilogue: row = m0 + wr*64 + m*16 + fq*4 + r, col = n0 + wc*64 + n*16 + fr
#pragma unroll
  for (int m = 0; m < 4; ++m) {
#pragma unroll
    for (int n = 0; n < 4; ++n) {
      int col = n0 + wc * 64 + n * 16 + fr;
      float bv = bias[col];
      if constexpr (EPI == 2) {
        int sec = col / 768;
        int c = col - sec * 768;
        int hh = c >> 6, dd = c & 63;
#pragma unroll
        for (int r = 0; r < 4; ++r) {
          int row = m0 + wr * 64 + m * 16 + fq * 4 + r;
          int bb2 = row >> 12, ss = row & 4095;
          size_t bhh = (size_t)(bb2 * Hc + hh);
          u16 val = f2b(acc[m][n][r] + bv);
          if (sec == 0) Qh[(bhh * Sc + ss) * 64 + dd] = val;
          else if (sec == 1) Kh[(bhh * Sc + ss) * 64 + dd] = val;
          else VhT[(bhh * 64 + dd) * Sc + ss] = val;
        }
      } else {
#pragma unroll
        for (int r = 0; r < 4; ++r) {
          int row = m0 + wr * 64 + m * 16 + fq * 4 + r;
          float v = acc[m][n][r] + bv;
          v = 0.5f * v * (1.f + erff(v * 0.70710678118654752f));
          Cb[(size_t)row * N + col] = f2b(v);
        }
      }
    }
  }
}

// ================================================================ gemmQ
// 128x128 tile, BK=64, 4 waves (2M x 2N), wave-tile 64x64, 64KB LDS
// -> 2 blocks/CU. 4-phase counted-vmcnt schedule. bf16 out + bias.
__global__ __launch_bounds__(256, 2)
void gemmQ(const u16* __restrict__ A, const u16* __restrict__ Bt,
           const float* __restrict__ bias, u16* __restrict__ Cb,
           int M, int N, int K)
{
  __shared__ u16 As[2][128 * 64];   // 32 KB
  __shared__ u16 Bs[2][128 * 64];   // 32 KB
  const int tid = threadIdx.x;
  const int wid = tid >> 6, lane = tid & 63;
  const int fr = lane & 15, fq = lane >> 4;
  const int wr = wid >> 1, wc = wid & 1;

  int nwg = gridDim.x * gridDim.y;
  int orig = blockIdx.y * gridDim.x + blockIdx.x;
  int swz = (nwg & 7) ? orig : (orig & 7) * (nwg >> 3) + (orig >> 3);
  int bx = swz % gridDim.x, by = swz / gridDim.x;
  const int m0 = by * 128, n0 = bx * 128;

  const u16* asrc[4];
  const u16* bsrc[4];
#pragma unroll
  for (int p = 0; p < 4; ++p) {
    int ci = p * 256 + tid;
    int r = ci >> 3, c = (ci & 7) ^ (r & 7);
    asrc[p] = A + (size_t)(m0 + r) * K + c * 8;
    bsrc[p] = Bt + (size_t)(n0 + r) * K + c * 8;
  }
  auto stageA = [&](int buf, int k0) {
#pragma unroll
    for (int p = 0; p < 4; ++p)
      gload_lds16(asrc[p] + k0, &As[buf][(p * 256 + tid) * 8]);
  };
  auto stageB = [&](int buf, int k0) {
#pragma unroll
    for (int p = 0; p < 4; ++p)
      gload_lds16(bsrc[p] + k0, &Bs[buf][(p * 256 + tid) * 8]);
  };

  f32x4 acc[4][4] = {};
  const int arow = wr * 64 + fr;
  const int brow = wc * 64 + fr;

  stageA(0, 0);  stageB(0, 0);
  stageA(1, 64); stageB(1, 64);
  asm volatile("s_waitcnt vmcnt(8)" ::: "memory");
  __builtin_amdgcn_sched_barrier(0);
  __builtin_amdgcn_s_barrier();

  const int nt = K >> 6;
  for (int kt = 0; kt < nt; ++kt) {
    const u16* ab = As[kt & 1];
    const u16* bb = Bs[kt & 1];
    bf16x8 aA[2][2], aB[2][2], bA[2][2], bB[2][2];

#pragma unroll
    for (int f = 0; f < 2; ++f)
#pragma unroll
      for (int kh = 0; kh < 2; ++kh) {
        int rowa = arow + f * 16;
        aA[f][kh] = *(const bf16x8*)(ab + rowa * 64 + (((kh * 4 + fq) ^ (rowa & 7)) << 3));
        int rowb = brow + f * 16;
        bA[f][kh] = *(const bf16x8*)(bb + rowb * 64 + (((kh * 4 + fq) ^ (rowb & 7)) << 3));
      }
    __builtin_amdgcn_s_setprio(1);
#pragma unroll
    for (int m = 0; m < 2; ++m)
#pragma unroll
      for (int n = 0; n < 2; ++n)
#pragma unroll
        for (int kh = 0; kh < 2; ++kh)
          acc[m][n] = __builtin_amdgcn_mfma_f32_16x16x32_bf16(aA[m][kh], bA[n][kh], acc[m][n], 0, 0, 0);
    __builtin_amdgcn_s_setprio(0);

#pragma unroll
    for (int f = 0; f < 2; ++f)
#pragma unroll
      for (int kh = 0; kh < 2; ++kh) {
        int rowb = brow + 32 + f * 16;
        bB[f][kh] = *(const bf16x8*)(bb + rowb * 64 + (((kh * 4 + fq) ^ (rowb & 7)) << 3));
      }
    __builtin_amdgcn_s_setprio(1);
#pragma unroll
    for (int m = 0; m < 2; ++m)
#pragma unroll
      for (int n = 0; n < 2; ++n)
#pragma unroll
        for (int kh = 0; kh < 2; ++kh)
          acc[m][n + 2] = __builtin_amdgcn_mfma_f32_16x16x32_bf16(aA[m][kh], bB[n][kh], acc[m][n + 2], 0, 0, 0);
    __builtin_amdgcn_s_setprio(0);
    asm volatile("s_waitcnt lgkmcnt(0)" ::: "memory");
    __builtin_amdgcn_sched_barrier(0);
    __builtin_amdgcn_s_barrier();

    if (kt + 2 < nt) stageB(kt & 1, (kt + 2) * 64);
#pragma unroll
    for (int f = 0; f < 2; ++f)
#pragma unroll
      for (int kh = 0; kh < 2; ++kh) {
        int rowa = arow + 32 + f * 16;
        aB[f][kh] = *(const bf16x8*)(ab + rowa * 64 + (((kh * 4 + fq) ^ (rowa & 7)) << 3));
      }
    __builtin_amdgcn_s_setprio(1);
#pragma unroll
    for (int m = 0; m < 2; ++m)
#pragma unroll
      for (int n = 0; n < 2; ++n)
#pragma unroll
        for (int kh = 0; kh < 2; ++kh)
          acc[m + 2][n] = __builtin_amdgcn_mfma_f32_16x16x32_bf16(aB[m][kh], bA[n][kh], acc[m + 2][n], 0, 0, 0);
    __builtin_amdgcn_s_setprio(0);
    asm volatile("s_waitcnt lgkmcnt(0)" ::: "memory");
    __builtin_amdgcn_sched_barrier(0);
    __builtin_amdgcn_s_barrier();

    if (kt + 2 < nt) stageA(kt & 1, (kt + 2) * 64);
    __builtin_amdgcn_s_setprio(1);
#pragma unroll
    for (int m = 0; m < 2; ++m)
#pragma unroll
      for (int n = 0; n < 2; ++n)
#pragma unroll
        for (int kh = 0; kh < 2; ++kh)
          acc[m + 2][n + 2] = __builtin_amdgcn_mfma_f32_16x16x32_bf16(aB[m][kh], bB[n][kh], acc[m + 2][n + 2], 0, 0, 0);
    __builtin_amdgcn_s_setprio(0);
    if (kt + 1 < nt) {
      if (kt + 2 < nt) asm volatile("s_waitcnt vmcnt(8)" ::: "memory");
      else             asm volatile("s_waitcnt vmcnt(0)" ::: "memory");
      __builtin_amdgcn_sched_barrier(0);
      __builtin_amdgcn_s_barrier();
    }
  }

#pragma unroll
  for (int m = 0; m < 4; ++m) {
#pragma unroll
    for (int n = 0; n < 4; ++n) {
      int col = n0 + wc * 64 + n * 16 + fr;
      float bv = bias[col];
#pragma unroll
      for (int r = 0; r < 4; ++r) {
        int row = m0 + wr * 64 + m * 16 + fq * 4 + r;
        Cb[(size_t)row * N + col] = f2b(acc[m][n][r] + bv);
      }
    }
  }
}

// ---------------------------------------------------------------- all-weights transpose f32->bf16
// v3: 64x64 tiles; float4 reads (256B rows); 16B/lane uint4 writes ->
// 1KB per wave store (8 rows x 128B). LDS read banks (8a+2j+b)%32 = 2-way (free).
__global__ __launch_bounds__(256)
void wtrans_all(const float* __restrict__ Wq, const float* __restrict__ Wk,
                const float* __restrict__ Wv, const float* __restrict__ Wo,
                const float* __restrict__ W1, const float* __restrict__ W2,
                u16* __restrict__ wqkvT, u16* __restrict__ woT,
                u16* __restrict__ w1T, u16* __restrict__ w2T)
{
  int bx = blockIdx.x;
  size_t l = blockIdx.y;
  size_t wsq = l * 768 * 768, wff = l * 768 * 3072;
  const float* in; u16* out; int K, N, ntx, t; float scale = 1.f;
  if (bx < 144)       { in = Wq + wsq; out = wqkvT + l * 2304 * 768;           K = 768;  N = 768;  ntx = 12; t = bx;        scale = 0.125f; }
  else if (bx < 288)  { in = Wk + wsq; out = wqkvT + l * 2304 * 768 + 589824;  K = 768;  N = 768;  ntx = 12; t = bx - 144;  }
  else if (bx < 432)  { in = Wv + wsq; out = wqkvT + l * 2304 * 768 + 1179648; K = 768;  N = 768;  ntx = 12; t = bx - 288;  }
  else if (bx < 576)  { in = Wo + wsq; out = woT + l * 768 * 768;              K = 768;  N = 768;  ntx = 12; t = bx - 432;  }
  else if (bx < 1152) { in = W1 + wff; out = w1T + l * 3072 * 768;             K = 768;  N = 3072; ntx = 48; t = bx - 576;  }
  else                { in = W2 + wff; out = w2T + l * 768 * 3072;             K = 3072; N = 768;  ntx = 12; t = bx - 1152; }
  int n0 = (t % ntx) * 64, k0 = (t / ntx) * 64;
  __shared__ float tl[64][65];
  int tid = threadIdx.x;
  // read: 64 rows x 64 f32, 256B contiguous per row
  int kr = tid >> 4, nc = (tid & 15) * 4;
#pragma unroll
  for (int kk = 0; kk < 4; ++kk) {
    float4 v = *(const float4*)(in + (size_t)(k0 + kk * 16 + kr) * N + n0 + nc);
    float* d = &tl[kk * 16 + kr][nc];
    d[0] = v.x; d[1] = v.y; d[2] = v.z; d[3] = v.w;
  }
  __syncthreads();
  // write: lane owns 8 consecutive k (16B) of row n; wave = 8 rows x 128B = 1KB/store
  int k8 = (tid & 7) * 8, nb = tid >> 3;
#pragma unroll
  for (int half = 0; half < 2; ++half) {
    int n = nb + half * 32;
    unsigned pk0 = (unsigned)f2b(tl[k8 + 0][n] * scale) | ((unsigned)f2b(tl[k8 + 1][n] * scale) << 16);
    unsigned pk1 = (unsigned)f2b(tl[k8 + 2][n] * scale) | ((unsigned)f2b(tl[k8 + 3][n] * scale) << 16);
    unsigned pk2 = (unsigned)f2b(tl[k8 + 4][n] * scale) | ((unsigned)f2b(tl[k8 + 5][n] * scale) << 16);
    unsigned pk3 = (unsigned)f2b(tl[k8 + 6][n] * scale) | ((unsigned)f2b(tl[k8 + 7][n] * scale) << 16);
    uint4 pk; pk.x = pk0; pk.y = pk1; pk.z = pk2; pk.w = pk3;
    *(uint4*)(out + (size_t)(n0 + n) * K + k0 + k8) = pk;
  }
}

__global__ void pack_bias(const float* __restrict__ bq, const float* __restrict__ bk,
                          const float* __restrict__ bv, float* __restrict__ bqkv)
{
  int i = blockIdx.x * 256 + threadIdx.x;
  if (i >= Lc * 2304) return;
  int l = i / 2304, j = i % 2304;
  float v = (j < 768) ? bq[(size_t)l * 768 + j] * 0.125f
          : (j < 1536) ? bk[(size_t)l * 768 + j - 768]
                       : bv[(size_t)l * 768 + j - 1536];
  bqkv[i] = v;
}

// ---------------------------------------------------------------- block reduce helper
DEV void breduce2(float& a, float& b) {
  __shared__ float ra[4], rbv[4];
  for (int off = 32; off > 0; off >>= 1) {
    a += __shfl_down(a, off);
    b += __shfl_down(b, off);
  }
  int lane = threadIdx.x & 63, wid = threadIdx.x >> 6;
  if (lane == 0) { ra[wid] = a; rbv[wid] = b; }
  __syncthreads();
  a = ra[0] + ra[1] + ra[2] + ra[3];
  b = rbv[0] + rbv[1] + rbv[2] + rbv[3];
}

// ---------------------------------------------------------------- embed + LN0
__global__ __launch_bounds__(256)
void embed_ln(const int* __restrict__ ids, const float* __restrict__ ew,
              const float* __restrict__ ep, const float* __restrict__ gs,
              const float* __restrict__ gb, float* __restrict__ hout, u16* __restrict__ hb)
{
  int row = blockIdx.x;
  int spos = row & (Sc - 1);
  int id = ids[row];
  int tid = threadIdx.x;
  float x[3], sum = 0.f, ss = 0.f;
#pragma unroll
  for (int j = 0; j < 3; ++j) {
    int i = tid + j * 256;
    x[j] = ew[(size_t)id * Dc + i] + ep[(size_t)spos * Dc + i];
    sum += x[j]; ss += x[j] * x[j];
  }
  breduce2(sum, ss);
  float mean = sum * (1.f / Dc);
  float var = ss * (1.f / Dc) - mean * mean;
  float inv = rsqrtf(var + 1e-12f);
#pragma unroll
  for (int j = 0; j < 3; ++j) {
    int i = tid + j * 256;
    float y = (x[j] - mean) * inv * gs[i] + gb[i];
    hout[(size_t)row * Dc + i] = y;
    hb[(size_t)row * Dc + i] = f2b(y);
  }
}

// ---------------------------------------------------------------- residual + LN
// one wave per row; float4/ushort4 vector loads; no __syncthreads.
__global__ __launch_bounds__(256)
void ln_res(const float* __restrict__ X, const u16* __restrict__ Rb,
            const float* __restrict__ gs, const float* __restrict__ gb,
            float* __restrict__ Yf, u16* __restrict__ Yb)
{
  const int wid = threadIdx.x >> 6, lane = threadIdx.x & 63;
  const int row = blockIdx.x * 4 + wid;
  const float* xr = X + (size_t)row * Dc;
  const u16*   rr = Rb + (size_t)row * Dc;
  float x[12];
  float sum = 0.f, ss = 0.f;
#pragma unroll
  for (int p = 0; p < 3; ++p) {
    int c = p * 256 + lane * 4;
    float4 xv = *(const float4*)(xr + c);
    ushort4 rv = *(const ushort4*)(rr + c);
    float v0 = xv.x + b2f(rv.x);
    float v1 = xv.y + b2f(rv.y);
    float v2 = xv.z + b2f(rv.z);
    float v3 = xv.w + b2f(rv.w);
    x[p * 4 + 0] = v0; x[p * 4 + 1] = v1; x[p * 4 + 2] = v2; x[p * 4 + 3] = v3;
    sum += (v0 + v1) + (v2 + v3);
    ss  += (v0 * v0 + v1 * v1) + (v2 * v2 + v3 * v3);
  }
#pragma unroll
  for (int off = 1; off < 64; off <<= 1) {
    sum += __shfl_xor(sum, off);
    ss  += __shfl_xor(ss, off);
  }
  float mean = sum * (1.f / Dc);
  float var = ss * (1.f / Dc) - mean * mean;
  float inv = rsqrtf(var + 1e-12f);
#pragma unroll
  for (int p = 0; p < 3; ++p) {
    int c = p * 256 + lane * 4;
    float4 gv = *(const float4*)(gs + c);
    float4 bv = *(const float4*)(gb + c);
    float y0 = (x[p * 4 + 0] - mean) * inv * gv.x + bv.x;
    float y1 = (x[p * 4 + 1] - mean) * inv * gv.y + bv.y;
    float y2 = (x[p * 4 + 2] - mean) * inv * gv.z + bv.z;
    float y3 = (x[p * 4 + 3] - mean) * inv * gv.w + bv.w;
    float4 yo; yo.x = y0; yo.y = y1; yo.z = y2; yo.w = y3;
    *(float4*)(Yf + (size_t)row * Dc + c) = yo;
    ushort4 pk; pk.x = f2b(y0); pk.y = f2b(y1); pk.z = f2b(y2); pk.w = f2b(y3);
    *(ushort4*)(Yb + (size_t)row * Dc + c) = pk;
  }
}

// ---------------------------------------------------------------- fused attention body:
// blocks 0..767: global-block flash attention (kc = bx&15, g = (bx>>4)&1, bh = bx>>5)
// blocks 768..2291: mid-block sparse attention (independent work, disjoint attnb rows)
__global__ __launch_bounds__(256)
void gattn_fm(const u16* __restrict__ Qh, const u16* __restrict__ Kh,
              const u16* __restrict__ VhT, const int* __restrict__ rb,
              float* __restrict__ part, u16* __restrict__ attnb)
{
  __shared__ u16 pb[4][16 * 136];
  __shared__ float ob[4][16][64];
  __shared__ float mlb[4][2][16];
  const int wid = threadIdx.x >> 6, lane = threadIdx.x & 63;
  const int fr = lane & 15, fq = lane >> 4;
  const int bxg = blockIdx.x;

  if (bxg < 768) {
    // ---- flash part
    const int kc = bxg & 15, g = (bxg >> 4) & 1, bh = bxg >> 5;
    const int qrow = g ? (NBc - 1) * BSc : 0;

    const u16* Qb = Qh + ((size_t)bh * Sc + qrow) * 64;
    const u16* Kb = Kh + (size_t)bh * Sc * 64;
    const u16* Vt = VhT + (size_t)bh * 64 * Sc;

    bf16x8 qa0 = *(const bf16x8*)(Qb + fr * 64 + fq * 8);
    bf16x8 qa1 = *(const bf16x8*)(Qb + fr * 64 + 32 + fq * 8);

    float m[4], l[4];
    f32x4 o[4] = {};
#pragma unroll
    for (int r = 0; r < 4; ++r) { m[r] = -3.4e38f; l[r] = 0.f; }

    u16* pbw = pb[wid];
    const int s0w = kc * 256 + wid * 64;

    for (int it = 0; it < 2; ++it) {
      const int sb = s0w + it * 32;
      f32x4 s[2];
#pragma unroll
      for (int t = 0; t < 2; ++t) {
        const u16* kr = Kb + (size_t)(sb + t * 16 + fr) * 64 + fq * 8;
        bf16x8 kb0 = *(const bf16x8*)(kr);
        bf16x8 kb1 = *(const bf16x8*)(kr + 32);
        f32x4 a = {};
        a = __builtin_amdgcn_mfma_f32_16x16x32_bf16(qa0, kb0, a, 0, 0, 0);
        a = __builtin_amdgcn_mfma_f32_16x16x32_bf16(qa1, kb1, a, 0, 0, 0);
        s[t] = a;
      }
#pragma unroll
      for (int r = 0; r < 4; ++r) {
        float pm = fmaxf(s[0][r], s[1][r]);
#pragma unroll
        for (int off = 1; off < 16; off <<= 1) pm = fmaxf(pm, __shfl_xor(pm, off));
        float nm = fmaxf(m[r], pm);
        float sc = __expf(m[r] - nm);
        m[r] = nm;
        float e0 = __expf(s[0][r] - nm), e1 = __expf(s[1][r] - nm);
        float ps = e0 + e1;
#pragma unroll
        for (int off = 1; off < 16; off <<= 1) ps += __shfl_xor(ps, off);
        l[r] = l[r] * sc + ps;
#pragma unroll
        for (int nn = 0; nn < 4; ++nn) o[nn][r] *= sc;
        pbw[(fq * 4 + r) * 136 + fr] = f2b(e0);
        pbw[(fq * 4 + r) * 136 + 16 + fr] = f2b(e1);
      }
      asm volatile("s_waitcnt lgkmcnt(0)" ::: "memory");
      __builtin_amdgcn_sched_barrier(0);
      bf16x8 pa = *(const bf16x8*)(pbw + fr * 136 + fq * 8);
#pragma unroll
      for (int nn = 0; nn < 4; ++nn) {
        bf16x8 vb = *(const bf16x8*)(Vt + (size_t)(nn * 16 + fr) * Sc + sb + fq * 8);
        o[nn] = __builtin_amdgcn_mfma_f32_16x16x32_bf16(pa, vb, o[nn], 0, 0, 0);
      }
    }

#pragma unroll
    for (int nn = 0; nn < 4; ++nn)
#pragma unroll
      for (int r = 0; r < 4; ++r)
        ob[wid][fq * 4 + r][nn * 16 + fr] = o[nn][r];
    if (fr == 0) {
#pragma unroll
      for (int r = 0; r < 4; ++r) {
        mlb[wid][0][fq * 4 + r] = m[r];
        mlb[wid][1][fq * 4 + r] = l[r];
      }
    }
    __syncthreads();

    float* pp = part + (size_t)(((bh * 2 + g) * 16) + kc) * 1056;
    int tid = threadIdx.x;
#pragma unroll
    for (int k = 0; k < 4; ++k) {
      int oidx = tid + k * 256;
      int q = oidx >> 6, d = oidx & 63;
      float M = fmaxf(fmaxf(mlb[0][0][q], mlb[1][0][q]), fmaxf(mlb[2][0][q], mlb[3][0][q]));
      float O = 0.f, L = 0.f;
#pragma unroll
      for (int w = 0; w < 4; ++w) {
        float f = __expf(mlb[w][0][q] - M);
        O += f * ob[w][q][d];
        L += f * mlb[w][1][q];
      }
      pp[q * 64 + d] = O;
      if (d == 0) { pp[1024 + q] = M; pp[1040 + q] = L; }
    }
    return;
  }

  // ---- mid-block sparse attention
  const int w = (bxg - 768) * 4 + wid;
  const int n = w % 254, bh = w / 254;
  const int b = bh / Hc, h = bh % Hc;

  int idx[7];
  idx[0] = 0; idx[1] = NBc - 1; idx[2] = n; idx[3] = n + 1; idx[4] = n + 2;
  idx[5] = rb[n * NRc]; idx[6] = rb[n * NRc + 1];

  const u16* Qb = Qh + ((size_t)bh * Sc + (n + 1) * BSc) * 64;
  const u16* Kb = Kh + (size_t)bh * Sc * 64;
  const u16* Vt = VhT + (size_t)bh * 64 * Sc;

  bf16x8 qa0 = *(const bf16x8*)(Qb + fr * 64 + fq * 8);
  bf16x8 qa1 = *(const bf16x8*)(Qb + fr * 64 + 32 + fq * 8);

  f32x4 s[7];
#pragma unroll
  for (int t = 0; t < 7; ++t) {
    const u16* kr = Kb + ((size_t)idx[t] * BSc + fr) * 64 + fq * 8;
    bf16x8 kb0 = *(const bf16x8*)(kr);
    bf16x8 kb1 = *(const bf16x8*)(kr + 32);
    f32x4 a = {};
    a = __builtin_amdgcn_mfma_f32_16x16x32_bf16(qa0, kb0, a, 0, 0, 0);
    a = __builtin_amdgcn_mfma_f32_16x16x32_bf16(qa1, kb1, a, 0, 0, 0);
    s[t] = a;
  }

  float mx[4], sm[4];
#pragma unroll
  for (int r = 0; r < 4; ++r) {
    mx[r] = s[0][r];
#pragma unroll
    for (int t = 1; t < 7; ++t) mx[r] = fmaxf(mx[r], s[t][r]);
  }
#pragma unroll
  for (int off = 1; off < 16; off <<= 1)
#pragma unroll
    for (int r = 0; r < 4; ++r) mx[r] = fmaxf(mx[r], __shfl_xor(mx[r], off));
#pragma unroll
  for (int r = 0; r < 4; ++r) sm[r] = 0.f;
#pragma unroll
  for (int t = 0; t < 7; ++t)
#pragma unroll
    for (int r = 0; r < 4; ++r) { float e = expf(s[t][r] - mx[r]); s[t][r] = e; sm[r] += e; }
#pragma unroll
  for (int off = 1; off < 16; off <<= 1)
#pragma unroll
    for (int r = 0; r < 4; ++r) sm[r] += __shfl_xor(sm[r], off);
  float inv[4];
#pragma unroll
  for (int r = 0; r < 4; ++r) inv[r] = 1.f / sm[r];

  u16* pbw = pb[wid];
#pragma unroll
  for (int t = 0; t < 7; ++t)
#pragma unroll
    for (int r = 0; r < 4; ++r)
      pbw[(fq * 4 + r) * 136 + t * 16 + fr] = f2b(s[t][r] * inv[r]);
  for (int i = lane; i < 16 * 24; i += 64) {
    int rr = i / 24, cc = 112 + i % 24;
    pbw[rr * 136 + cc] = 0;
  }
  __syncthreads();

  f32x4 o[4] = {};
#pragma unroll
  for (int ks = 0; ks < 4; ++ks) {
    bf16x8 pa = *(const bf16x8*)(pbw + fr * 136 + ks * 32 + fq * 8);
    int t = ks * 2 + (fq >> 1);
    int tt = (t < 7) ? t : 0;
    size_t voff = (size_t)idx[tt] * BSc + (fq & 1) * 8;
#pragma unroll
    for (int nn = 0; nn < 4; ++nn) {
      bf16x8 vb = *(const bf16x8*)(Vt + (size_t)(nn * 16 + fr) * Sc + voff);
      o[nn] = __builtin_amdgcn_mfma_f32_16x16x32_bf16(pa, vb, o[nn], 0, 0, 0);
    }
  }

  size_t rbase = (size_t)b * Sc + (n + 1) * BSc;
#pragma unroll
  for (int nn = 0; nn < 4; ++nn)
#pragma unroll
    for (int r = 0; r < 4; ++r)
      attnb[(rbase + fq * 4 + r) * Dc + h * 64 + nn * 16 + fr] = f2b(o[nn][r]);
}

// combine 16 key-chunk partials -> attnb rows. grid 48 = (bh,g)
__global__ __launch_bounds__(256)
void gattn_reduce(const float* __restrict__ part, u16* __restrict__ attnb)
{
  int idx = blockIdx.x;       // bh*2+g
  int bh = idx >> 1, g = idx & 1;
  int b = bh / Hc, h = bh % Hc;
  int tid = threadIdx.x;
  const float* pbase = part + (size_t)idx * 16 * 1056;
#pragma unroll
  for (int k = 0; k < 4; ++k) {
    int oidx = tid + k * 256;
    int q = oidx >> 6, d = oidx & 63;
    float M = -3.4e38f;
#pragma unroll
    for (int c = 0; c < 16; ++c) M = fmaxf(M, pbase[c * 1056 + 1024 + q]);
    float O = 0.f, L = 0.f;
#pragma unroll
    for (int c = 0; c < 16; ++c) {
      float f = __expf(pbase[c * 1056 + 1024 + q] - M);
      O += f * pbase[c * 1056 + q * 64 + d];
      L += f * pbase[c * 1056 + 1040 + q];
    }
    int srow = (g ? (NBc - 1) * BSc : 0) + q;
    attnb[((size_t)(b * Sc + srow)) * Dc + h * 64 + d] = f2b(O / L);
  }
}

// ---------------------------------------------------------------- final heads
__global__ __launch_bounds__(256)
void logits_k(const float* __restrict__ h, const float* __restrict__ sw,
              const float* __restrict__ ew, float* __restrict__ out)
{
  int row = blockIdx.x;
  int tid = threadIdx.x;
  float s1 = 0.f, s2 = 0.f;
#pragma unroll
  for (int j = 0; j < 3; ++j) {
    int i = tid + j * 256;
    float x = h[(size_t)row * Dc + i];
    s1 += x * sw[i]; s2 += x * ew[i];
  }
  breduce2(s1, s2);
  if (tid == 0) { out[row] = s1; out[Mr + row] = s2; }
}

// pooled = tanh(h[:,0] @ Wp + bp), parallel GEMV: grid (12, B)
__global__ __launch_bounds__(256)
void pooled_k(const float* __restrict__ h, const float* __restrict__ Wp,
              const float* __restrict__ bp, float* __restrict__ pooled)
{
  int b = blockIdx.y, j0 = blockIdx.x * 64;
  int jl = threadIdx.x & 63, kp = threadIdx.x >> 6;
  __shared__ float hr[768];
  __shared__ float part[4][64];
  for (int i = threadIdx.x; i < 768; i += 256) hr[i] = h[(size_t)b * Sc * Dc + i];
  __syncthreads();
  float a0 = 0.f, a1 = 0.f, a2 = 0.f, a3 = 0.f;
  const float* wp = Wp + (size_t)(kp * 192) * 768 + j0 + jl;
  const float* hk = hr + kp * 192;
#pragma unroll 4
  for (int k = 0; k < 192; k += 4) {
    a0 += hk[k]     * wp[(size_t)k * 768];
    a1 += hk[k + 1] * wp[(size_t)(k + 1) * 768];
    a2 += hk[k + 2] * wp[(size_t)(k + 2) * 768];
    a3 += hk[k + 3] * wp[(size_t)(k + 3) * 768];
  }
  part[kp][jl] = a0 + a1 + a2 + a3;
  __syncthreads();
  if (threadIdx.x < 64) {
    float s = part[0][jl] + part[1][jl] + part[2][jl] + part[3][jl] + bp[j0 + jl];
    pooled[b * 768 + j0 + jl] = tanhf(s);
  }
}

// d1 = relu(pooled @ Wd1 + bd1); disc = d1 @ Wd2 + bd2
__global__ __launch_bounds__(256)
void head2(const float* __restrict__ pooled, const float* __restrict__ Wd1,
           const float* __restrict__ bd1, const float* __restrict__ Wd2,
           const float* __restrict__ bd2, float* __restrict__ out)
{
  __shared__ float pl[1536];
  __shared__ float part[40][6];
  __shared__ float d1[40];
  int tid = threadIdx.x;
  for (int i = tid; i < 1536; i += 256) pl[i] = pooled[i];
  __syncthreads();
  if (tid < 240) {
    int p = tid / 6, s = tid % 6;
    int b = p / 20, u = p % 20;
    float a = 0.f;
    for (int k = s * 128; k < s * 128 + 128; ++k) a += pl[b * 768 + k] * Wd1[(size_t)k * 20 + u];
    part[p][s] = a;
  }
  __syncthreads();
  if (tid < 40) {
    float a = bd1[tid % 20];
#pragma unroll
    for (int s = 0; s < 6; ++s) a += part[tid][s];
    d1[tid] = fmaxf(a, 0.f);
  }
  __syncthreads();
  if (tid < 4) {
    int b = tid >> 1, o = tid & 1;
    float a = bd2[o];
#pragma unroll
    for (int k = 0; k < 20; ++k) a += d1[b * 20 + k] * Wd2[k * 2 + o];
    out[2 * Mr + b * 2 + o] = a;
  }
}

// ================================================================ host
extern "C" void kernel_launch(void* const* d_in, const int* in_sizes, int n_in,
                              void* d_out, int out_size, void* d_ws, size_t ws_size,
                              hipStream_t stream)
{
  (void)in_sizes; (void)n_in; (void)out_size; (void)ws_size;
  const int*   ids   = (const int*)d_in[0];
  const int*   rbp   = (const int*)d_in[1];
  const float* emb_w = (const float*)d_in[2];
  const float* emb_p = (const float*)d_in[3];
  const float* ln0s  = (const float*)d_in[4];
  const float* ln0b  = (const float*)d_in[5];
  const float* Wq    = (const float*)d_in[6];
  const float* bq    = (const float*)d_in[7];
  const float* Wk    = (const float*)d_in[8];
  const float* bk    = (const float*)d_in[9];
  const float* Wv    = (const float*)d_in[10];
  const float* bv    = (const float*)d_in[11];
  const float* Wo    = (const float*)d_in[12];
  const float* bo    = (const float*)d_in[13];
  const float* ln1s  = (const float*)d_in[14];
  const float* ln1b  = (const float*)d_in[15];
  const float* W1    = (const float*)d_in[16];
  const float* b1    = (const float*)d_in[17];
  const float* W2    = (const float*)d_in[18];
  const float* b2    = (const float*)d_in[19];
  const float* ln2s  = (const float*)d_in[20];
  const float* ln2b  = (const float*)d_in[21];
  const float* Wp    = (const float*)d_in[22];
  const float* bp    = (const float*)d_in[23];
  const float* sw    = (const float*)d_in[24];
  const float* ewv   = (const float*)d_in[25];
  const float* Wd1   = (const float*)d_in[26];
  const float* bd1   = (const float*)d_in[27];
  const float* Wd2   = (const float*)d_in[28];
  const float* bd2   = (const float*)d_in[29];
  float* out = (float*)d_out;

  unsigned char* pc = (unsigned char*)d_ws;
  auto carve = [&](size_t bytes) {
    void* r = (void*)pc;
    pc += (bytes + 255) & ~(size_t)255;
    return r;
  };
  u16*   wqkvT = (u16*)carve((size_t)Lc * 2304 * 768 * 2);
  u16*   woT   = (u16*)carve((size_t)Lc * 768 * 768 * 2);
  u16*   w1T   = (u16*)carve((size_t)Lc * 3072 * 768 * 2);
  u16*   w2T   = (u16*)carve((size_t)Lc * 768 * 3072 * 2);
  float* bqkv  = (float*)carve((size_t)Lc * 2304 * 4);
  float* h     = (float*)carve((size_t)Mr * Dc * 4);
  u16*   hb    = (u16*)carve((size_t)Mr * Dc * 2);
  u16*   Qh    = (u16*)carve((size_t)Mr * Dc * 2);
  u16*   Kh    = (u16*)carve((size_t)Mr * Dc * 2);
  u16*   VhT   = (u16*)carve((size_t)Mr * Dc * 2);
  u16*   attnb = (u16*)carve((size_t)Mr * Dc * 2);
  u16*   c0b   = (u16*)carve((size_t)Mr * Dc * 2);
  float* pool2 = (float*)carve((size_t)Bc * Dc * 4);
  float* m1ws  = (float*)carve((size_t)Mr * DFFc * 2);
  u16*   m1    = (u16*)m1ws;
  float* part  = (float*)((unsigned char*)m1ws + (size_t)13 * 1024 * 1024);

  pack_bias<<<(Lc * 2304 + 255) / 256, 256, 0, stream>>>(bq, bk, bv, bqkv);
  // all 12 layers' weight transposes in one parallel launch (64x64 tiles, 1KB/wave stores)
  wtrans_all<<<dim3(1728, Lc), 256, 0, stream>>>(Wq, Wk, Wv, Wo, W1, W2,
                                                 wqkvT, woT, w1T, w2T);
  embed_ln<<<Mr, 256, 0, stream>>>(ids, emb_w, emb_p, ln0s, ln0b, h, hb);

  for (int l = 0; l < Lc; ++l) {
    // fused QKV projection (128x256 pipelined) -> per-head bf16 Q/K (+V^T)
    gemmP<2><<<dim3(9, 64), 512, 0, stream>>>(hb, wqkvT + (size_t)l * 2304 * 768,
                                              bqkv + (size_t)l * 2304,
                                              nullptr, Qh, Kh, VhT, Mr, 2304, 768);
    // flash (768 blocks) + mid sparse attention (1524 blocks) in one launch
    gattn_fm<<<768 + 1524, 256, 0, stream>>>(Qh, Kh, VhT, rbp, part, attnb);
    // combine flash partials (48 blocks, L2-resident)
    gattn_reduce<<<48, 256, 0, stream>>>(part, attnb);
    // output projection (128x128, 2 blocks/CU) -> bf16
    gemmQ<<<dim3(6, 64), 256, 0, stream>>>(attnb, woT + (size_t)l * 768 * 768,
                                           bo + (size_t)l * 768, c0b, Mr, 768, 768);
    ln_res<<<Mr / 4, 256, 0, stream>>>(h, c0b, ln1s + (size_t)l * 768, ln1b + (size_t)l * 768, h, hb);
    // FFN
    gemmP<1><<<dim3(12, 64), 512, 0, stream>>>(hb, w1T + (size_t)l * 3072 * 768,
                                               b1 + (size_t)l * 3072,
                                               m1, nullptr, nullptr, nullptr,
                                               Mr, 3072, 768);
    gemmQ<<<dim3(6, 64), 256, 0, stream>>>(m1, w2T + (size_t)l * 768 * 3072,
                                           b2 + (size_t)l * 768, c0b, Mr, 768, 3072);
    ln_res<<<Mr / 4, 256, 0, stream>>>(h, c0b, ln2s + (size_t)l * 768, ln2b + (size_t)l * 768, h, hb);
  }

  logits_k<<<Mr, 256, 0, stream>>>(h, sw, ewv, out);
  pooled_k<<<dim3(12, Bc), 256, 0, stream>>>(h, Wp, bp, pool2);
  head2<<<1, 256, 0, stream>>>(pool2, Wd1, bd1, Wd2, bd2, out);
}

// Round 7
// 3579.691 us; speedup vs baseline: 1.0104x; 1.0104x over previous
//
#include <hip/hip_runtime.h>

#define DEV __device__ __forceinline__

typedef unsigned short u16;
typedef short bf16x8 __attribute__((ext_vector_type(8)));
typedef float f32x4 __attribute__((ext_vector_type(4)));
typedef unsigned u32x4 __attribute__((ext_vector_type(4)));

constexpr int Bc = 2, Sc = 4096, Dc = 768, Hc = 12, Lc = 12;
constexpr int BSc = 16, NBc = 256, NRc = 2, DFFc = 3072;
constexpr int Mr = Bc * Sc; // 8192 token rows

DEV u16 f2b(float f) {
  unsigned u = __builtin_bit_cast(unsigned, f);
  u += 0x7fffu + ((u >> 16) & 1u);
  return (u16)(u >> 16);
}
DEV float b2f(u16 u) { return __builtin_bit_cast(float, (unsigned)u << 16); }

DEV void gload_lds16(const void* g, void* l) {
  __builtin_amdgcn_global_load_lds((const __attribute__((address_space(1))) void*)g,
                                   (__attribute__((address_space(3))) void*)l, 16, 0, 0);
}

// ================================================================ gemmP
// 128(M)x256(N) tile, BK=64, 8 waves (2M x 4N), wave-tile 64x64.
// Double-buffered LDS (96KB), 4 fine phases/K-tile, counted vmcnt(6),
// T2 both-sides XOR swizzle, T5 setprio, bijective XCD swizzle.
// C = A[M,K] @ Bt[N,K]^T + bias.
// EPI 1: GELU->bf16 Cb | 2: QKV scatter (Qh/Kh/VhT).
template<int EPI>
__global__ __launch_bounds__(512, 1)
void gemmP(const u16* __restrict__ A, const u16* __restrict__ Bt,
           const float* __restrict__ bias, u16* __restrict__ Cb,
           u16* __restrict__ Qh, u16* __restrict__ Kh,
           u16* __restrict__ VhT, int M, int N, int K)
{
  __shared__ u16 As[2][128 * 64];   // 32 KB
  __shared__ u16 Bs[2][256 * 64];   // 64 KB
  const int tid = threadIdx.x;
  const int wid = tid >> 6, lane = tid & 63;
  const int fr = lane & 15, fq = lane >> 4;
  const int wr = wid >> 2, wc = wid & 3;

  // bijective XCD swizzle (nwg % 8 == 0 for all our launches)
  int nwg = gridDim.x * gridDim.y;
  int orig = blockIdx.y * gridDim.x + blockIdx.x;
  int swz = (nwg & 7) ? orig : (orig & 7) * (nwg >> 3) + (orig >> 3);
  int bx = swz % gridDim.x, by = swz / gridDim.x;
  const int m0 = by * 128, n0 = bx * 256;

  const u16* asrc[2];
  const u16* bsrc[4];
#pragma unroll
  for (int p = 0; p < 2; ++p) {
    int ci = p * 512 + tid;
    int r = ci >> 3, c = (ci & 7) ^ (r & 7);
    asrc[p] = A + (size_t)(m0 + r) * K + c * 8;
  }
#pragma unroll
  for (int p = 0; p < 4; ++p) {
    int ci = p * 512 + tid;
    int r = ci >> 3, c = (ci & 7) ^ (r & 7);
    bsrc[p] = Bt + (size_t)(n0 + r) * K + c * 8;
  }
  auto stageA = [&](int buf, int k0) {
#pragma unroll
    for (int p = 0; p < 2; ++p)
      gload_lds16(asrc[p] + k0, &As[buf][(p * 512 + tid) * 8]);
  };
  auto stageB = [&](int buf, int k0) {
#pragma unroll
    for (int p = 0; p < 4; ++p)
      gload_lds16(bsrc[p] + k0, &Bs[buf][(p * 512 + tid) * 8]);
  };

  f32x4 acc[4][4] = {};
  const int arow = wr * 64 + fr;
  const int brow = wc * 64 + fr;

  stageA(0, 0);  stageB(0, 0);    // tile 0: 6 loads
  stageA(1, 64); stageB(1, 64);   // tile 1: 6 loads
  asm volatile("s_waitcnt vmcnt(6)" ::: "memory");   // tile 0 ready
  __builtin_amdgcn_sched_barrier(0);
  __builtin_amdgcn_s_barrier();

  const int nt = K >> 6;
  for (int kt = 0; kt < nt; ++kt) {
    const u16* ab = As[kt & 1];
    const u16* bb = Bs[kt & 1];
    bf16x8 aA[2][2], aB[2][2], bA[2][2], bB[2][2];  // [frag][khalf]

    // ---- phase 0: read A(m0,1) + B(n0,1); MFMA quadrant (m01 x n01)
#pragma unroll
    for (int f = 0; f < 2; ++f)
#pragma unroll
      for (int kh = 0; kh < 2; ++kh) {
        int rowa = arow + f * 16;
        aA[f][kh] = *(const bf16x8*)(ab + rowa * 64 + (((kh * 4 + fq) ^ (rowa & 7)) << 3));
        int rowb = brow + f * 16;
        bA[f][kh] = *(const bf16x8*)(bb + rowb * 64 + (((kh * 4 + fq) ^ (rowb & 7)) << 3));
      }
    __builtin_amdgcn_s_setprio(1);
#pragma unroll
    for (int m = 0; m < 2; ++m)
#pragma unroll
      for (int n = 0; n < 2; ++n)
#pragma unroll
        for (int kh = 0; kh < 2; ++kh)
          acc[m][n] = __builtin_amdgcn_mfma_f32_16x16x32_bf16(aA[m][kh], bA[n][kh], acc[m][n], 0, 0, 0);
    __builtin_amdgcn_s_setprio(0);

    // ---- phase 1: read B(n2,3); MFMA (m01 x n23); barrier (B fully vacated)
#pragma unroll
    for (int f = 0; f < 2; ++f)
#pragma unroll
      for (int kh = 0; kh < 2; ++kh) {
        int rowb = brow + 32 + f * 16;
        bB[f][kh] = *(const bf16x8*)(bb + rowb * 64 + (((kh * 4 + fq) ^ (rowb & 7)) << 3));
      }
    __builtin_amdgcn_s_setprio(1);
#pragma unroll
    for (int m = 0; m < 2; ++m)
#pragma unroll
      for (int n = 0; n < 2; ++n)
#pragma unroll
        for (int kh = 0; kh < 2; ++kh)
          acc[m][n + 2] = __builtin_amdgcn_mfma_f32_16x16x32_bf16(aA[m][kh], bB[n][kh], acc[m][n + 2], 0, 0, 0);
    __builtin_amdgcn_s_setprio(0);
    asm volatile("s_waitcnt lgkmcnt(0)" ::: "memory");
    __builtin_amdgcn_sched_barrier(0);
    __builtin_amdgcn_s_barrier();

    // ---- phase 2: stage next B into vacated region; read A(m2,3); MFMA (m23 x n01)
    if (kt + 2 < nt) stageB(kt & 1, (kt + 2) * 64);
#pragma unroll
    for (int f = 0; f < 2; ++f)
#pragma unroll
      for (int kh = 0; kh < 2; ++kh) {
        int rowa = arow + 32 + f * 16;
        aB[f][kh] = *(const bf16x8*)(ab + rowa * 64 + (((kh * 4 + fq) ^ (rowa & 7)) << 3));
      }
    __builtin_amdgcn_s_setprio(1);
#pragma unroll
    for (int m = 0; m < 2; ++m)
#pragma unroll
      for (int n = 0; n < 2; ++n)
#pragma unroll
        for (int kh = 0; kh < 2; ++kh)
          acc[m + 2][n] = __builtin_amdgcn_mfma_f32_16x16x32_bf16(aB[m][kh], bA[n][kh], acc[m + 2][n], 0, 0, 0);
    __builtin_amdgcn_s_setprio(0);
    asm volatile("s_waitcnt lgkmcnt(0)" ::: "memory");
    __builtin_amdgcn_sched_barrier(0);
    __builtin_amdgcn_s_barrier();

    // ---- phase 3: stage next A (A fully vacated); MFMA (m23 x n23); tile gate
    if (kt + 2 < nt) stageA(kt & 1, (kt + 2) * 64);
    __builtin_amdgcn_s_setprio(1);
#pragma unroll
    for (int m = 0; m < 2; ++m)
#pragma unroll
      for (int n = 0; n < 2; ++n)
#pragma unroll
        for (int kh = 0; kh < 2; ++kh)
          acc[m + 2][n + 2] = __builtin_amdgcn_mfma_f32_16x16x32_bf16(aB[m][kh], bB[n][kh], acc[m + 2][n + 2], 0, 0, 0);
    __builtin_amdgcn_s_setprio(0);
    if (kt + 1 < nt) {
      if (kt + 2 < nt) asm volatile("s_waitcnt vmcnt(6)" ::: "memory");  // next tile ready, 6 newest in flight
      else             asm volatile("s_waitcnt vmcnt(0)" ::: "memory");
      __builtin_amdgcn_sched_barrier(0);
      __builtin_amdgcn_s_barrier();
    }
  }

  // epilogue: row = m0 + wr*64 + m*16 + fq*4 + r, col = n0 + wc*64 + n*16 + fr
#pragma unroll
  for (int m = 0; m < 4; ++m) {
#pragma unroll
    for (int n = 0; n < 4; ++n) {
      int col = n0 + wc * 64 + n * 16 + fr;
      float bv = bias[col];
      if constexpr (EPI == 2) {
        int sec = col / 768;
        int c = col - sec * 768;
        int hh = c >> 6, dd = c & 63;
#pragma unroll
        for (int r = 0; r < 4; ++r) {
          int row = m0 + wr * 64 + m * 16 + fq * 4 + r;
          int bb2 = row >> 12, ss = row & 4095;
          size_t bhh = (size_t)(bb2 * Hc + hh);
          u16 val = f2b(acc[m][n][r] + bv);
          if (sec == 0) Qh[(bhh * Sc + ss) * 64 + dd] = val;
          else if (sec == 1) Kh[(bhh * Sc + ss) * 64 + dd] = val;
          else VhT[(bhh * 64 + dd) * Sc + ss] = val;
        }
      } else {
#pragma unroll
        for (int r = 0; r < 4; ++r) {
          int row = m0 + wr * 64 + m * 16 + fq * 4 + r;
          float v = acc[m][n][r] + bv;
          v = 0.5f * v * (1.f + erff(v * 0.70710678118654752f));
          Cb[(size_t)row * N + col] = f2b(v);
        }
      }
    }
  }
}

// ================================================================ gemmQ
// 128x128 tile, BK=64, 4 waves (2M x 2N), wave-tile 64x64, 64KB LDS
// -> 2 blocks/CU. 4-phase counted-vmcnt schedule. bf16 out + bias.
__global__ __launch_bounds__(256, 2)
void gemmQ(const u16* __restrict__ A, const u16* __restrict__ Bt,
           const float* __restrict__ bias, u16* __restrict__ Cb,
           int M, int N, int K)
{
  __shared__ u16 As[2][128 * 64];   // 32 KB
  __shared__ u16 Bs[2][128 * 64];   // 32 KB
  const int tid = threadIdx.x;
  const int wid = tid >> 6, lane = tid & 63;
  const int fr = lane & 15, fq = lane >> 4;
  const int wr = wid >> 1, wc = wid & 1;

  int nwg = gridDim.x * gridDim.y;
  int orig = blockIdx.y * gridDim.x + blockIdx.x;
  int swz = (nwg & 7) ? orig : (orig & 7) * (nwg >> 3) + (orig >> 3);
  int bx = swz % gridDim.x, by = swz / gridDim.x;
  const int m0 = by * 128, n0 = bx * 128;

  const u16* asrc[4];
  const u16* bsrc[4];
#pragma unroll
  for (int p = 0; p < 4; ++p) {
    int ci = p * 256 + tid;
    int r = ci >> 3, c = (ci & 7) ^ (r & 7);
    asrc[p] = A + (size_t)(m0 + r) * K + c * 8;
    bsrc[p] = Bt + (size_t)(n0 + r) * K + c * 8;
  }
  auto stageA = [&](int buf, int k0) {
#pragma unroll
    for (int p = 0; p < 4; ++p)
      gload_lds16(asrc[p] + k0, &As[buf][(p * 256 + tid) * 8]);
  };
  auto stageB = [&](int buf, int k0) {
#pragma unroll
    for (int p = 0; p < 4; ++p)
      gload_lds16(bsrc[p] + k0, &Bs[buf][(p * 256 + tid) * 8]);
  };

  f32x4 acc[4][4] = {};
  const int arow = wr * 64 + fr;
  const int brow = wc * 64 + fr;

  stageA(0, 0);  stageB(0, 0);
  stageA(1, 64); stageB(1, 64);
  asm volatile("s_waitcnt vmcnt(8)" ::: "memory");
  __builtin_amdgcn_sched_barrier(0);
  __builtin_amdgcn_s_barrier();

  const int nt = K >> 6;
  for (int kt = 0; kt < nt; ++kt) {
    const u16* ab = As[kt & 1];
    const u16* bb = Bs[kt & 1];
    bf16x8 aA[2][2], aB[2][2], bA[2][2], bB[2][2];

#pragma unroll
    for (int f = 0; f < 2; ++f)
#pragma unroll
      for (int kh = 0; kh < 2; ++kh) {
        int rowa = arow + f * 16;
        aA[f][kh] = *(const bf16x8*)(ab + rowa * 64 + (((kh * 4 + fq) ^ (rowa & 7)) << 3));
        int rowb = brow + f * 16;
        bA[f][kh] = *(const bf16x8*)(bb + rowb * 64 + (((kh * 4 + fq) ^ (rowb & 7)) << 3));
      }
    __builtin_amdgcn_s_setprio(1);
#pragma unroll
    for (int m = 0; m < 2; ++m)
#pragma unroll
      for (int n = 0; n < 2; ++n)
#pragma unroll
        for (int kh = 0; kh < 2; ++kh)
          acc[m][n] = __builtin_amdgcn_mfma_f32_16x16x32_bf16(aA[m][kh], bA[n][kh], acc[m][n], 0, 0, 0);
    __builtin_amdgcn_s_setprio(0);

#pragma unroll
    for (int f = 0; f < 2; ++f)
#pragma unroll
      for (int kh = 0; kh < 2; ++kh) {
        int rowb = brow + 32 + f * 16;
        bB[f][kh] = *(const bf16x8*)(bb + rowb * 64 + (((kh * 4 + fq) ^ (rowb & 7)) << 3));
      }
    __builtin_amdgcn_s_setprio(1);
#pragma unroll
    for (int m = 0; m < 2; ++m)
#pragma unroll
      for (int n = 0; n < 2; ++n)
#pragma unroll
        for (int kh = 0; kh < 2; ++kh)
          acc[m][n + 2] = __builtin_amdgcn_mfma_f32_16x16x32_bf16(aA[m][kh], bB[n][kh], acc[m][n + 2], 0, 0, 0);
    __builtin_amdgcn_s_setprio(0);
    asm volatile("s_waitcnt lgkmcnt(0)" ::: "memory");
    __builtin_amdgcn_sched_barrier(0);
    __builtin_amdgcn_s_barrier();

    if (kt + 2 < nt) stageB(kt & 1, (kt + 2) * 64);
#pragma unroll
    for (int f = 0; f < 2; ++f)
#pragma unroll
      for (int kh = 0; kh < 2; ++kh) {
        int rowa = arow + 32 + f * 16;
        aB[f][kh] = *(const bf16x8*)(ab + rowa * 64 + (((kh * 4 + fq) ^ (rowa & 7)) << 3));
      }
    __builtin_amdgcn_s_setprio(1);
#pragma unroll
    for (int m = 0; m < 2; ++m)
#pragma unroll
      for (int n = 0; n < 2; ++n)
#pragma unroll
        for (int kh = 0; kh < 2; ++kh)
          acc[m + 2][n] = __builtin_amdgcn_mfma_f32_16x16x32_bf16(aB[m][kh], bA[n][kh], acc[m + 2][n], 0, 0, 0);
    __builtin_amdgcn_s_setprio(0);
    asm volatile("s_waitcnt lgkmcnt(0)" ::: "memory");
    __builtin_amdgcn_sched_barrier(0);
    __builtin_amdgcn_s_barrier();

    if (kt + 2 < nt) stageA(kt & 1, (kt + 2) * 64);
    __builtin_amdgcn_s_setprio(1);
#pragma unroll
    for (int m = 0; m < 2; ++m)
#pragma unroll
      for (int n = 0; n < 2; ++n)
#pragma unroll
        for (int kh = 0; kh < 2; ++kh)
          acc[m + 2][n + 2] = __builtin_amdgcn_mfma_f32_16x16x32_bf16(aB[m][kh], bB[n][kh], acc[m + 2][n + 2], 0, 0, 0);
    __builtin_amdgcn_s_setprio(0);
    if (kt + 1 < nt) {
      if (kt + 2 < nt) asm volatile("s_waitcnt vmcnt(8)" ::: "memory");
      else             asm volatile("s_waitcnt vmcnt(0)" ::: "memory");
      __builtin_amdgcn_sched_barrier(0);
      __builtin_amdgcn_s_barrier();
    }
  }

#pragma unroll
  for (int m = 0; m < 4; ++m) {
#pragma unroll
    for (int n = 0; n < 4; ++n) {
      int col = n0 + wc * 64 + n * 16 + fr;
      float bv = bias[col];
#pragma unroll
      for (int r = 0; r < 4; ++r) {
        int row = m0 + wr * 64 + m * 16 + fq * 4 + r;
        Cb[(size_t)row * N + col] = f2b(acc[m][n][r] + bv);
      }
    }
  }
}

// ---------------------------------------------------------------- all-weights transpose f32->bf16
// v4: 64x64 tiles; float4 reads (256B rows); 16B/lane NON-TEMPORAL writes
// via native ext_vector u32x4 (touch-once stream - skip L2/L3 allocation).
__global__ __launch_bounds__(256)
void wtrans_all(const float* __restrict__ Wq, const float* __restrict__ Wk,
                const float* __restrict__ Wv, const float* __restrict__ Wo,
                const float* __restrict__ W1, const float* __restrict__ W2,
                u16* __restrict__ wqkvT, u16* __restrict__ woT,
                u16* __restrict__ w1T, u16* __restrict__ w2T)
{
  int bx = blockIdx.x;
  size_t l = blockIdx.y;
  size_t wsq = l * 768 * 768, wff = l * 768 * 3072;
  const float* in; u16* out; int K, N, ntx, t; float scale = 1.f;
  if (bx < 144)       { in = Wq + wsq; out = wqkvT + l * 2304 * 768;           K = 768;  N = 768;  ntx = 12; t = bx;        scale = 0.125f; }
  else if (bx < 288)  { in = Wk + wsq; out = wqkvT + l * 2304 * 768 + 589824;  K = 768;  N = 768;  ntx = 12; t = bx - 144;  }
  else if (bx < 432)  { in = Wv + wsq; out = wqkvT + l * 2304 * 768 + 1179648; K = 768;  N = 768;  ntx = 12; t = bx - 288;  }
  else if (bx < 576)  { in = Wo + wsq; out = woT + l * 768 * 768;              K = 768;  N = 768;  ntx = 12; t = bx - 432;  }
  else if (bx < 1152) { in = W1 + wff; out = w1T + l * 3072 * 768;             K = 768;  N = 3072; ntx = 48; t = bx - 576;  }
  else                { in = W2 + wff; out = w2T + l * 768 * 3072;             K = 3072; N = 768;  ntx = 12; t = bx - 1152; }
  int n0 = (t % ntx) * 64, k0 = (t / ntx) * 64;
  __shared__ float tl[64][65];
  int tid = threadIdx.x;
  // read: 64 rows x 64 f32, 256B contiguous per row
  int kr = tid >> 4, nc = (tid & 15) * 4;
#pragma unroll
  for (int kk = 0; kk < 4; ++kk) {
    float4 v = *(const float4*)(in + (size_t)(k0 + kk * 16 + kr) * N + n0 + nc);
    float* d = &tl[kk * 16 + kr][nc];
    d[0] = v.x; d[1] = v.y; d[2] = v.z; d[3] = v.w;
  }
  __syncthreads();
  // write: lane owns 8 consecutive k (16B) of row n; wave = 8 rows x 128B = 1KB/store
  int k8 = (tid & 7) * 8, nb = tid >> 3;
#pragma unroll
  for (int half = 0; half < 2; ++half) {
    int n = nb + half * 32;
    u32x4 pk;
    pk.x = (unsigned)f2b(tl[k8 + 0][n] * scale) | ((unsigned)f2b(tl[k8 + 1][n] * scale) << 16);
    pk.y = (unsigned)f2b(tl[k8 + 2][n] * scale) | ((unsigned)f2b(tl[k8 + 3][n] * scale) << 16);
    pk.z = (unsigned)f2b(tl[k8 + 4][n] * scale) | ((unsigned)f2b(tl[k8 + 5][n] * scale) << 16);
    pk.w = (unsigned)f2b(tl[k8 + 6][n] * scale) | ((unsigned)f2b(tl[k8 + 7][n] * scale) << 16);
    __builtin_nontemporal_store(pk, (u32x4*)(out + (size_t)(n0 + n) * K + k0 + k8));
  }
}

__global__ void pack_bias(const float* __restrict__ bq, const float* __restrict__ bk,
                          const float* __restrict__ bv, float* __restrict__ bqkv)
{
  int i = blockIdx.x * 256 + threadIdx.x;
  if (i >= Lc * 2304) return;
  int l = i / 2304, j = i % 2304;
  float v = (j < 768) ? bq[(size_t)l * 768 + j] * 0.125f
          : (j < 1536) ? bk[(size_t)l * 768 + j - 768]
                       : bv[(size_t)l * 768 + j - 1536];
  bqkv[i] = v;
}

// ---------------------------------------------------------------- block reduce helper
DEV void breduce2(float& a, float& b) {
  __shared__ float ra[4], rbv[4];
  for (int off = 32; off > 0; off >>= 1) {
    a += __shfl_down(a, off);
    b += __shfl_down(b, off);
  }
  int lane = threadIdx.x & 63, wid = threadIdx.x >> 6;
  if (lane == 0) { ra[wid] = a; rbv[wid] = b; }
  __syncthreads();
  a = ra[0] + ra[1] + ra[2] + ra[3];
  b = rbv[0] + rbv[1] + rbv[2] + rbv[3];
}

// ---------------------------------------------------------------- embed + LN0
__global__ __launch_bounds__(256)
void embed_ln(const int* __restrict__ ids, const float* __restrict__ ew,
              const float* __restrict__ ep, const float* __restrict__ gs,
              const float* __restrict__ gb, float* __restrict__ hout, u16* __restrict__ hb)
{
  int row = blockIdx.x;
  int spos = row & (Sc - 1);
  int id = ids[row];
  int tid = threadIdx.x;
  float x[3], sum = 0.f, ss = 0.f;
#pragma unroll
  for (int j = 0; j < 3; ++j) {
    int i = tid + j * 256;
    x[j] = ew[(size_t)id * Dc + i] + ep[(size_t)spos * Dc + i];
    sum += x[j]; ss += x[j] * x[j];
  }
  breduce2(sum, ss);
  float mean = sum * (1.f / Dc);
  float var = ss * (1.f / Dc) - mean * mean;
  float inv = rsqrtf(var + 1e-12f);
#pragma unroll
  for (int j = 0; j < 3; ++j) {
    int i = tid + j * 256;
    float y = (x[j] - mean) * inv * gs[i] + gb[i];
    hout[(size_t)row * Dc + i] = y;
    hb[(size_t)row * Dc + i] = f2b(y);
  }
}

// ---------------------------------------------------------------- residual + LN
// one wave per row; float4/ushort4 vector loads; no __syncthreads.
__global__ __launch_bounds__(256)
void ln_res(const float* __restrict__ X, const u16* __restrict__ Rb,
            const float* __restrict__ gs, const float* __restrict__ gb,
            float* __restrict__ Yf, u16* __restrict__ Yb)
{
  const int wid = threadIdx.x >> 6, lane = threadIdx.x & 63;
  const int row = blockIdx.x * 4 + wid;
  const float* xr = X + (size_t)row * Dc;
  const u16*   rr = Rb + (size_t)row * Dc;
  float x[12];
  float sum = 0.f, ss = 0.f;
#pragma unroll
  for (int p = 0; p < 3; ++p) {
    int c = p * 256 + lane * 4;
    float4 xv = *(const float4*)(xr + c);
    ushort4 rv = *(const ushort4*)(rr + c);
    float v0 = xv.x + b2f(rv.x);
    float v1 = xv.y + b2f(rv.y);
    float v2 = xv.z + b2f(rv.z);
    float v3 = xv.w + b2f(rv.w);
    x[p * 4 + 0] = v0; x[p * 4 + 1] = v1; x[p * 4 + 2] = v2; x[p * 4 + 3] = v3;
    sum += (v0 + v1) + (v2 + v3);
    ss  += (v0 * v0 + v1 * v1) + (v2 * v2 + v3 * v3);
  }
#pragma unroll
  for (int off = 1; off < 64; off <<= 1) {
    sum += __shfl_xor(sum, off);
    ss  += __shfl_xor(ss, off);
  }
  float mean = sum * (1.f / Dc);
  float var = ss * (1.f / Dc) - mean * mean;
  float inv = rsqrtf(var + 1e-12f);
#pragma unroll
  for (int p = 0; p < 3; ++p) {
    int c = p * 256 + lane * 4;
    float4 gv = *(const float4*)(gs + c);
    float4 bv = *(const float4*)(gb + c);
    float y0 = (x[p * 4 + 0] - mean) * inv * gv.x + bv.x;
    float y1 = (x[p * 4 + 1] - mean) * inv * gv.y + bv.y;
    float y2 = (x[p * 4 + 2] - mean) * inv * gv.z + bv.z;
    float y3 = (x[p * 4 + 3] - mean) * inv * gv.w + bv.w;
    float4 yo; yo.x = y0; yo.y = y1; yo.z = y2; yo.w = y3;
    *(float4*)(Yf + (size_t)row * Dc + c) = yo;
    ushort4 pk; pk.x = f2b(y0); pk.y = f2b(y1); pk.z = f2b(y2); pk.w = f2b(y3);
    *(ushort4*)(Yb + (size_t)row * Dc + c) = pk;
  }
}

// ---------------------------------------------------------------- global-block flash attention
// grid (16 kchunks, 2 g, 24 bh), 256 thr = 4 waves; wave handles 64 keys
// (2 iters x 32 keys). Layouts mirror mid_attn2 (verified).
__global__ __launch_bounds__(256)
void gattn_flash(const u16* __restrict__ Qh, const u16* __restrict__ Kh,
                 const u16* __restrict__ VhT, float* __restrict__ part)
{
  __shared__ u16 pb[4][16 * 136];
  __shared__ float ob[4][16][64];
  __shared__ float mlb[4][2][16];
  const int kc = blockIdx.x, g = blockIdx.y, bh = blockIdx.z;
  const int wid = threadIdx.x >> 6, lane = threadIdx.x & 63;
  const int fr = lane & 15, fq = lane >> 4;
  const int qrow = g ? (NBc - 1) * BSc : 0;

  const u16* Qb = Qh + ((size_t)bh * Sc + qrow) * 64;
  const u16* Kb = Kh + (size_t)bh * Sc * 64;
  const u16* Vt = VhT + (size_t)bh * 64 * Sc;

  bf16x8 qa0 = *(const bf16x8*)(Qb + fr * 64 + fq * 8);
  bf16x8 qa1 = *(const bf16x8*)(Qb + fr * 64 + 32 + fq * 8);

  float m[4], l[4];
  f32x4 o[4] = {};
#pragma unroll
  for (int r = 0; r < 4; ++r) { m[r] = -3.4e38f; l[r] = 0.f; }

  u16* pbw = pb[wid];
  const int s0w = kc * 256 + wid * 64;

  for (int it = 0; it < 2; ++it) {
    const int sb = s0w + it * 32;
    f32x4 s[2];
#pragma unroll
    for (int t = 0; t < 2; ++t) {
      const u16* kr = Kb + (size_t)(sb + t * 16 + fr) * 64 + fq * 8;
      bf16x8 kb0 = *(const bf16x8*)(kr);
      bf16x8 kb1 = *(const bf16x8*)(kr + 32);
      f32x4 a = {};
      a = __builtin_amdgcn_mfma_f32_16x16x32_bf16(qa0, kb0, a, 0, 0, 0);
      a = __builtin_amdgcn_mfma_f32_16x16x32_bf16(qa1, kb1, a, 0, 0, 0);
      s[t] = a;
    }
#pragma unroll
    for (int r = 0; r < 4; ++r) {
      float pm = fmaxf(s[0][r], s[1][r]);
#pragma unroll
      for (int off = 1; off < 16; off <<= 1) pm = fmaxf(pm, __shfl_xor(pm, off));
      float nm = fmaxf(m[r], pm);
      float sc = __expf(m[r] - nm);
      m[r] = nm;
      float e0 = __expf(s[0][r] - nm), e1 = __expf(s[1][r] - nm);
      float ps = e0 + e1;
#pragma unroll
      for (int off = 1; off < 16; off <<= 1) ps += __shfl_xor(ps, off);
      l[r] = l[r] * sc + ps;
#pragma unroll
      for (int nn = 0; nn < 4; ++nn) o[nn][r] *= sc;
      pbw[(fq * 4 + r) * 136 + fr] = f2b(e0);
      pbw[(fq * 4 + r) * 136 + 16 + fr] = f2b(e1);
    }
    asm volatile("s_waitcnt lgkmcnt(0)" ::: "memory");
    __builtin_amdgcn_sched_barrier(0);
    bf16x8 pa = *(const bf16x8*)(pbw + fr * 136 + fq * 8);
#pragma unroll
    for (int nn = 0; nn < 4; ++nn) {
      bf16x8 vb = *(const bf16x8*)(Vt + (size_t)(nn * 16 + fr) * Sc + sb + fq * 8);
      o[nn] = __builtin_amdgcn_mfma_f32_16x16x32_bf16(pa, vb, o[nn], 0, 0, 0);
    }
  }

#pragma unroll
  for (int nn = 0; nn < 4; ++nn)
#pragma unroll
    for (int r = 0; r < 4; ++r)
      ob[wid][fq * 4 + r][nn * 16 + fr] = o[nn][r];
  if (fr == 0) {
#pragma unroll
    for (int r = 0; r < 4; ++r) {
      mlb[wid][0][fq * 4 + r] = m[r];
      mlb[wid][1][fq * 4 + r] = l[r];
    }
  }
  __syncthreads();

  float* pp = part + (size_t)(((bh * 2 + g) * 16) + kc) * 1056;
  int tid = threadIdx.x;
#pragma unroll
  for (int k = 0; k < 4; ++k) {
    int oidx = tid + k * 256;
    int q = oidx >> 6, d = oidx & 63;
    float M = fmaxf(fmaxf(mlb[0][0][q], mlb[1][0][q]), fmaxf(mlb[2][0][q], mlb[3][0][q]));
    float O = 0.f, L = 0.f;
#pragma unroll
    for (int w = 0; w < 4; ++w) {
      float f = __expf(mlb[w][0][q] - M);
      O += f * ob[w][q][d];
      L += f * mlb[w][1][q];
    }
    pp[q * 64 + d] = O;
    if (d == 0) { pp[1024 + q] = M; pp[1040 + q] = L; }
  }
}

// ---------------------------------------------------------------- attn tail:
// blocks 0..47: combine key-chunk partials; blocks 48..: mid-block sparse attn
__global__ __launch_bounds__(256)
void attn_tail(const u16* __restrict__ Qh, const u16* __restrict__ Kh,
               const u16* __restrict__ VhT, const int* __restrict__ rb,
               const float* __restrict__ part, u16* __restrict__ attnb)
{
  if (blockIdx.x < 48) {
    int idx = blockIdx.x;       // bh*2+g
    int bh = idx >> 1, g = idx & 1;
    int b = bh / Hc, h = bh % Hc;
    int tid = threadIdx.x;
    const float* pbase = part + (size_t)idx * 16 * 1056;
#pragma unroll
    for (int k = 0; k < 4; ++k) {
      int oidx = tid + k * 256;
      int q = oidx >> 6, d = oidx & 63;
      float M = -3.4e38f;
#pragma unroll
      for (int c = 0; c < 16; ++c) M = fmaxf(M, pbase[c * 1056 + 1024 + q]);
      float O = 0.f, L = 0.f;
#pragma unroll
      for (int c = 0; c < 16; ++c) {
        float f = __expf(pbase[c * 1056 + 1024 + q] - M);
        O += f * pbase[c * 1056 + q * 64 + d];
        L += f * pbase[c * 1056 + 1040 + q];
      }
      int srow = (g ? (NBc - 1) * BSc : 0) + q;
      attnb[((size_t)(b * Sc + srow)) * Dc + h * 64 + d] = f2b(O / L);
    }
    return;
  }

  __shared__ u16 pb[4][16 * 136];
  const int wid = threadIdx.x >> 6, lane = threadIdx.x & 63;
  const int w = (blockIdx.x - 48) * 4 + wid;
  const int n = w % 254, bh = w / 254;
  const int b = bh / Hc, h = bh % Hc;
  const int fr = lane & 15, fq = lane >> 4;

  int idx[7];
  idx[0] = 0; idx[1] = NBc - 1; idx[2] = n; idx[3] = n + 1; idx[4] = n + 2;
  idx[5] = rb[n * NRc]; idx[6] = rb[n * NRc + 1];

  const u16* Qb = Qh + ((size_t)bh * Sc + (n + 1) * BSc) * 64;
  const u16* Kb = Kh + (size_t)bh * Sc * 64;
  const u16* Vt = VhT + (size_t)bh * 64 * Sc;

  bf16x8 qa0 = *(const bf16x8*)(Qb + fr * 64 + fq * 8);
  bf16x8 qa1 = *(const bf16x8*)(Qb + fr * 64 + 32 + fq * 8);

  f32x4 s[7];
#pragma unroll
  for (int t = 0; t < 7; ++t) {
    const u16* kr = Kb + ((size_t)idx[t] * BSc + fr) * 64 + fq * 8;
    bf16x8 kb0 = *(const bf16x8*)(kr);
    bf16x8 kb1 = *(const bf16x8*)(kr + 32);
    f32x4 a = {};
    a = __builtin_amdgcn_mfma_f32_16x16x32_bf16(qa0, kb0, a, 0, 0, 0);
    a = __builtin_amdgcn_mfma_f32_16x16x32_bf16(qa1, kb1, a, 0, 0, 0);
    s[t] = a;
  }

  float mx[4], sm[4];
#pragma unroll
  for (int r = 0; r < 4; ++r) {
    mx[r] = s[0][r];
#pragma unroll
    for (int t = 1; t < 7; ++t) mx[r] = fmaxf(mx[r], s[t][r]);
  }
#pragma unroll
  for (int off = 1; off < 16; off <<= 1)
#pragma unroll
    for (int r = 0; r < 4; ++r) mx[r] = fmaxf(mx[r], __shfl_xor(mx[r], off));
#pragma unroll
  for (int r = 0; r < 4; ++r) sm[r] = 0.f;
#pragma unroll
  for (int t = 0; t < 7; ++t)
#pragma unroll
    for (int r = 0; r < 4; ++r) { float e = expf(s[t][r] - mx[r]); s[t][r] = e; sm[r] += e; }
#pragma unroll
  for (int off = 1; off < 16; off <<= 1)
#pragma unroll
    for (int r = 0; r < 4; ++r) sm[r] += __shfl_xor(sm[r], off);
  float inv[4];
#pragma unroll
  for (int r = 0; r < 4; ++r) inv[r] = 1.f / sm[r];

  u16* pbw = pb[wid];
#pragma unroll
  for (int t = 0; t < 7; ++t)
#pragma unroll
    for (int r = 0; r < 4; ++r)
      pbw[(fq * 4 + r) * 136 + t * 16 + fr] = f2b(s[t][r] * inv[r]);
  for (int i = lane; i < 16 * 24; i += 64) {
    int rr = i / 24, cc = 112 + i % 24;
    pbw[rr * 136 + cc] = 0;
  }
  __syncthreads();

  f32x4 o[4] = {};
#pragma unroll
  for (int ks = 0; ks < 4; ++ks) {
    bf16x8 pa = *(const bf16x8*)(pbw + fr * 136 + ks * 32 + fq * 8);
    int t = ks * 2 + (fq >> 1);
    int tt = (t < 7) ? t : 0;
    size_t voff = (size_t)idx[tt] * BSc + (fq & 1) * 8;
#pragma unroll
    for (int nn = 0; nn < 4; ++nn) {
      bf16x8 vb = *(const bf16x8*)(Vt + (size_t)(nn * 16 + fr) * Sc + voff);
      o[nn] = __builtin_amdgcn_mfma_f32_16x16x32_bf16(pa, vb, o[nn], 0, 0, 0);
    }
  }

  size_t rbase = (size_t)b * Sc + (n + 1) * BSc;
#pragma unroll
  for (int nn = 0; nn < 4; ++nn)
#pragma unroll
    for (int r = 0; r < 4; ++r)
      attnb[(rbase + fq * 4 + r) * Dc + h * 64 + nn * 16 + fr] = f2b(o[nn][r]);
}

// ---------------------------------------------------------------- final heads
__global__ __launch_bounds__(256)
void logits_k(const float* __restrict__ h, const float* __restrict__ sw,
              const float* __restrict__ ew, float* __restrict__ out)
{
  int row = blockIdx.x;
  int tid = threadIdx.x;
  float s1 = 0.f, s2 = 0.f;
#pragma unroll
  for (int j = 0; j < 3; ++j) {
    int i = tid + j * 256;
    float x = h[(size_t)row * Dc + i];
    s1 += x * sw[i]; s2 += x * ew[i];
  }
  breduce2(s1, s2);
  if (tid == 0) { out[row] = s1; out[Mr + row] = s2; }
}

// pooled = tanh(h[:,0] @ Wp + bp), parallel GEMV: grid (12, B)
__global__ __launch_bounds__(256)
void pooled_k(const float* __restrict__ h, const float* __restrict__ Wp,
              const float* __restrict__ bp, float* __restrict__ pooled)
{
  int b = blockIdx.y, j0 = blockIdx.x * 64;
  int jl = threadIdx.x & 63, kp = threadIdx.x >> 6;
  __shared__ float hr[768];
  __shared__ float part[4][64];
  for (int i = threadIdx.x; i < 768; i += 256) hr[i] = h[(size_t)b * Sc * Dc + i];
  __syncthreads();
  float a0 = 0.f, a1 = 0.f, a2 = 0.f, a3 = 0.f;
  const float* wp = Wp + (size_t)(kp * 192) * 768 + j0 + jl;
  const float* hk = hr + kp * 192;
#pragma unroll 4
  for (int k = 0; k < 192; k += 4) {
    a0 += hk[k]     * wp[(size_t)k * 768];
    a1 += hk[k + 1] * wp[(size_t)(k + 1) * 768];
    a2 += hk[k + 2] * wp[(size_t)(k + 2) * 768];
    a3 += hk[k + 3] * wp[(size_t)(k + 3) * 768];
  }
  part[kp][jl] = a0 + a1 + a2 + a3;
  __syncthreads();
  if (threadIdx.x < 64) {
    float s = part[0][jl] + part[1][jl] + part[2][jl] + part[3][jl] + bp[j0 + jl];
    pooled[b * 768 + j0 + jl] = tanhf(s);
  }
}

// d1 = relu(pooled @ Wd1 + bd1); disc = d1 @ Wd2 + bd2
__global__ __launch_bounds__(256)
void head2(const float* __restrict__ pooled, const float* __restrict__ Wd1,
           const float* __restrict__ bd1, const float* __restrict__ Wd2,
           const float* __restrict__ bd2, float* __restrict__ out)
{
  __shared__ float pl[1536];
  __shared__ float part[40][6];
  __shared__ float d1[40];
  int tid = threadIdx.x;
  for (int i = tid; i < 1536; i += 256) pl[i] = pooled[i];
  __syncthreads();
  if (tid < 240) {
    int p = tid / 6, s = tid % 6;
    int b = p / 20, u = p % 20;
    float a = 0.f;
    for (int k = s * 128; k < s * 128 + 128; ++k) a += pl[b * 768 + k] * Wd1[(size_t)k * 20 + u];
    part[p][s] = a;
  }
  __syncthreads();
  if (tid < 40) {
    float a = bd1[tid % 20];
#pragma unroll
    for (int s = 0; s < 6; ++s) a += part[tid][s];
    d1[tid] = fmaxf(a, 0.f);
  }
  __syncthreads();
  if (tid < 4) {
    int b = tid >> 1, o = tid & 1;
    float a = bd2[o];
#pragma unroll
    for (int k = 0; k < 20; ++k) a += d1[b * 20 + k] * Wd2[k * 2 + o];
    out[2 * Mr + b * 2 + o] = a;
  }
}

// ================================================================ host
extern "C" void kernel_launch(void* const* d_in, const int* in_sizes, int n_in,
                              void* d_out, int out_size, void* d_ws, size_t ws_size,
                              hipStream_t stream)
{
  (void)in_sizes; (void)n_in; (void)out_size; (void)ws_size;
  const int*   ids   = (const int*)d_in[0];
  const int*   rbp   = (const int*)d_in[1];
  const float* emb_w = (const float*)d_in[2];
  const float* emb_p = (const float*)d_in[3];
  const float* ln0s  = (const float*)d_in[4];
  const float* ln0b  = (const float*)d_in[5];
  const float* Wq    = (const float*)d_in[6];
  const float* bq    = (const float*)d_in[7];
  const float* Wk    = (const float*)d_in[8];
  const float* bk    = (const float*)d_in[9];
  const float* Wv    = (const float*)d_in[10];
  const float* bv    = (const float*)d_in[11];
  const float* Wo    = (const float*)d_in[12];
  const float* bo    = (const float*)d_in[13];
  const float* ln1s  = (const float*)d_in[14];
  const float* ln1b  = (const float*)d_in[15];
  const float* W1    = (const float*)d_in[16];
  const float* b1    = (const float*)d_in[17];
  const float* W2    = (const float*)d_in[18];
  const float* b2    = (const float*)d_in[19];
  const float* ln2s  = (const float*)d_in[20];
  const float* ln2b  = (const float*)d_in[21];
  const float* Wp    = (const float*)d_in[22];
  const float* bp    = (const float*)d_in[23];
  const float* sw    = (const float*)d_in[24];
  const float* ewv   = (const float*)d_in[25];
  const float* Wd1   = (const float*)d_in[26];
  const float* bd1   = (const float*)d_in[27];
  const float* Wd2   = (const float*)d_in[28];
  const float* bd2   = (const float*)d_in[29];
  float* out = (float*)d_out;

  unsigned char* pc = (unsigned char*)d_ws;
  auto carve = [&](size_t bytes) {
    void* r = (void*)pc;
    pc += (bytes + 255) & ~(size_t)255;
    return r;
  };
  u16*   wqkvT = (u16*)carve((size_t)Lc * 2304 * 768 * 2);
  u16*   woT   = (u16*)carve((size_t)Lc * 768 * 768 * 2);
  u16*   w1T   = (u16*)carve((size_t)Lc * 3072 * 768 * 2);
  u16*   w2T   = (u16*)carve((size_t)Lc * 768 * 3072 * 2);
  float* bqkv  = (float*)carve((size_t)Lc * 2304 * 4);
  float* h     = (float*)carve((size_t)Mr * Dc * 4);
  u16*   hb    = (u16*)carve((size_t)Mr * Dc * 2);
  u16*   Qh    = (u16*)carve((size_t)Mr * Dc * 2);
  u16*   Kh    = (u16*)carve((size_t)Mr * Dc * 2);
  u16*   VhT   = (u16*)carve((size_t)Mr * Dc * 2);
  u16*   attnb = (u16*)carve((size_t)Mr * Dc * 2);
  u16*   c0b   = (u16*)carve((size_t)Mr * Dc * 2);
  float* pool2 = (float*)carve((size_t)Bc * Dc * 4);
  float* m1ws  = (float*)carve((size_t)Mr * DFFc * 2);
  u16*   m1    = (u16*)m1ws;
  float* part  = (float*)((unsigned char*)m1ws + (size_t)13 * 1024 * 1024);

  pack_bias<<<(Lc * 2304 + 255) / 256, 256, 0, stream>>>(bq, bk, bv, bqkv);
  // all 12 layers' weight transposes in one parallel launch (nt stores)
  wtrans_all<<<dim3(1728, Lc), 256, 0, stream>>>(Wq, Wk, Wv, Wo, W1, W2,
                                                 wqkvT, woT, w1T, w2T);
  embed_ln<<<Mr, 256, 0, stream>>>(ids, emb_w, emb_p, ln0s, ln0b, h, hb);

  for (int l = 0; l < Lc; ++l) {
    // fused QKV projection (128x256 pipelined) -> per-head bf16 Q/K (+V^T)
    gemmP<2><<<dim3(9, 64), 512, 0, stream>>>(hb, wqkvT + (size_t)l * 2304 * 768,
                                              bqkv + (size_t)l * 2304,
                                              nullptr, Qh, Kh, VhT, Mr, 2304, 768);
    // global blocks: fused MFMA flash attention (partials over 16 key-chunks)
    gattn_flash<<<dim3(16, 2, Bc * Hc), 256, 0, stream>>>(Qh, Kh, VhT, part);
    // combine partials (48 blocks) + mid-block sparse attention (1524 blocks)
    attn_tail<<<48 + 1524, 256, 0, stream>>>(Qh, Kh, VhT, rbp, part, attnb);
    // output projection (128x128, 2 blocks/CU) -> bf16
    gemmQ<<<dim3(6, 64), 256, 0, stream>>>(attnb, woT + (size_t)l * 768 * 768,
                                           bo + (size_t)l * 768, c0b, Mr, 768, 768);
    ln_res<<<Mr / 4, 256, 0, stream>>>(h, c0b, ln1s + (size_t)l * 768, ln1b + (size_t)l * 768, h, hb);
    // FFN
    gemmP<1><<<dim3(12, 64), 512, 0, stream>>>(hb, w1T + (size_t)l * 3072 * 768,
                                               b1 + (size_t)l * 3072,
                                               m1, nullptr, nullptr, nullptr,
                                               Mr, 3072, 768);
    gemmQ<<<dim3(6, 64), 256, 0, stream>>>(m1, w2T + (size_t)l * 768 * 3072,
                                           b2 + (size_t)l * 768, c0b, Mr, 768, 3072);
    ln_res<<<Mr / 4, 256, 0, stream>>>(h, c0b, ln2s + (size_t)l * 768, ln2b + (size_t)l * 768, h, hb);
  }

  logits_k<<<Mr, 256, 0, stream>>>(h, sw, ewv, out);
  pooled_k<<<dim3(12, Bc), 256, 0, stream>>>(h, Wp, bp, pool2);
  head2<<<1, 256, 0, stream>>>(pool2, Wd1, bd1, Wd2, bd2, out);
}